// Round 1
// baseline (1234.787 us; speedup 1.0000x reference)
//
#include <hip/hip_runtime.h>

#define HH 256
#define WW 256
#define CIN 16
#define KOUT 32
#define NIMG 32

#define TILE_H 64
#define TILE_W 32
#define KB 4            // output channels per block
#define CCHUNK 4        // input channels staged in LDS at a time
#define LDS_ROWS 66     // TILE_H + 2 halo
#define LDS_COLS 34     // TILE_W + 2 halo (written at offset +3)
#define LDS_STRIDE 44   // mult of 4 (16B-aligned float4), stride/4=11 odd -> <=2-way bank aliasing
#define THREADS 256

__global__ __launch_bounds__(THREADS, 3)
void conv2d_f32_tiled(const float* __restrict__ x,
                      const float* __restrict__ wts,
                      const float* __restrict__ bias,
                      float* __restrict__ out) {
    __shared__ __align__(16) float smem[CCHUNK][LDS_ROWS][LDS_STRIDE];

    const int tid = threadIdx.x;
    const int kg  = blockIdx.x;            // 0..7  (k-group, fastest for L2 reuse)
    const int sp  = blockIdx.y;            // 0..31 (4 h-tiles x 8 w-tiles)
    const int n   = blockIdx.z;            // 0..31
    const int hbase = (sp >> 3) * TILE_H;
    const int wbase = (sp & 7) * TILE_W;

    const int wlane = tid & 7;             // 8 groups of 4 output cols
    const int hlane = tid >> 3;            // 32 groups of 2 output rows
    const int h0 = hbase + 2 * hlane;
    const int w0 = wbase + 4 * wlane;

    float acc[KB][2][4];
#pragma unroll
    for (int kk = 0; kk < KB; ++kk)
#pragma unroll
        for (int dh = 0; dh < 2; ++dh)
#pragma unroll
            for (int w = 0; w < 4; ++w)
                acc[kk][dh][w] = 0.f;

    const float b0 = bias[0];

    for (int cc = 0; cc < CIN; cc += CCHUNK) {
        __syncthreads();
        // ---- stage CCHUNK channels of the (66 x 34) halo tile into LDS ----
        for (int idx = tid; idx < CCHUNK * LDS_ROWS * LDS_COLS; idx += THREADS) {
            int c   = idx / (LDS_ROWS * LDS_COLS);
            int rem = idx - c * (LDS_ROWS * LDS_COLS);
            int row = rem / LDS_COLS;
            int col = rem - row * LDS_COLS;
            int gh = hbase - 1 + row;
            int gw = wbase - 1 + col;
            float v = 0.f;
            if ((unsigned)gh < (unsigned)HH && (unsigned)gw < (unsigned)WW)
                v = x[(((n * CIN + cc + c) * HH + gh) * WW) + gw];
            smem[c][row][col + 3] = v;
        }
        __syncthreads();

        // ---- compute ----
#pragma unroll
        for (int c = 0; c < CCHUNK; ++c) {
            // block-uniform weight addresses -> scalar loads
            const float* wp = wts + ((size_t)(kg * KB) * CIN + (cc + c)) * 9;
            float wv[KB][9];
#pragma unroll
            for (int kk = 0; kk < KB; ++kk)
#pragma unroll
                for (int t = 0; t < 9; ++t)
                    wv[kk][t] = wp[kk * CIN * 9 + t];

            // 4 input rows x 6 cols per thread: b32 + b128 + b32 each row
            float4 xm[4];
            float  xl[4], xr[4];
#pragma unroll
            for (int rr = 0; rr < 4; ++rr) {
                const float* rowp = &smem[c][2 * hlane + rr][4 * wlane];
                xl[rr] = rowp[3];                                        // w0-1
                xm[rr] = *reinterpret_cast<const float4*>(rowp + 4);     // w0..w0+3 (16B aligned)
                xr[rr] = rowp[8];                                        // w0+4
            }

#pragma unroll
            for (int kk = 0; kk < KB; ++kk)
#pragma unroll
                for (int r = 0; r < 3; ++r)
#pragma unroll
                    for (int dh = 0; dh < 2; ++dh) {
                        const int rr = r + dh;
                        const float w0v = wv[kk][r * 3 + 0];
                        const float w1v = wv[kk][r * 3 + 1];
                        const float w2v = wv[kk][r * 3 + 2];
                        const float cm1 = xl[rr];
                        const float4 cm = xm[rr];
                        const float cp4 = xr[rr];
                        // s = 0 (input col = w0 + w - 1)
                        acc[kk][dh][0] += w0v * cm1;
                        acc[kk][dh][1] += w0v * cm.x;
                        acc[kk][dh][2] += w0v * cm.y;
                        acc[kk][dh][3] += w0v * cm.z;
                        // s = 1
                        acc[kk][dh][0] += w1v * cm.x;
                        acc[kk][dh][1] += w1v * cm.y;
                        acc[kk][dh][2] += w1v * cm.z;
                        acc[kk][dh][3] += w1v * cm.w;
                        // s = 2
                        acc[kk][dh][0] += w2v * cm.y;
                        acc[kk][dh][1] += w2v * cm.z;
                        acc[kk][dh][2] += w2v * cm.w;
                        acc[kk][dh][3] += w2v * cp4;
                    }
        }
    }

    // ---- epilogue: add bias[0] (reference adds scalar bias[0] to ALL channels) ----
#pragma unroll
    for (int kk = 0; kk < KB; ++kk) {
#pragma unroll
        for (int dh = 0; dh < 2; ++dh) {
            float4 v = make_float4(acc[kk][dh][0] + b0,
                                   acc[kk][dh][1] + b0,
                                   acc[kk][dh][2] + b0,
                                   acc[kk][dh][3] + b0);
            float* op = out + (((size_t)(n * KOUT + kg * KB + kk) * HH + (h0 + dh)) * WW) + w0;
            *reinterpret_cast<float4*>(op) = v;
        }
    }
}

extern "C" void kernel_launch(void* const* d_in, const int* in_sizes, int n_in,
                              void* d_out, int out_size, void* d_ws, size_t ws_size,
                              hipStream_t stream) {
    const float* x    = (const float*)d_in[0];
    const float* wts  = (const float*)d_in[1];
    const float* bias = (const float*)d_in[2];
    float* out = (float*)d_out;

    dim3 grid(KOUT / KB, (HH / TILE_H) * (WW / TILE_W), NIMG);  // (8, 32, 32)
    dim3 block(THREADS);
    conv2d_f32_tiled<<<grid, block, 0, stream>>>(x, wts, bias, out);
}

// Round 2
// 419.849 us; speedup vs baseline: 2.9410x; 2.9410x over previous
//
#include <hip/hip_runtime.h>

typedef __bf16 bf16x8 __attribute__((ext_vector_type(8)));
typedef float  f32x16 __attribute__((ext_vector_type(16)));

#define HH 256
#define WW 256
#define CIN 16
#define KOUT 32
#define NIMG 32
#define TILE_H 16
#define TILE_W 64
#define ROWS (TILE_H + 2)   // 18
#define COLS (TILE_W + 2)   // 66
#define THREADS 256

__device__ __forceinline__ ushort f2bf_rne(float v) {
    unsigned u = __float_as_uint(v);
    u += 0x7FFFu + ((u >> 16) & 1u);
    return (ushort)(u >> 16);
}

__global__ __launch_bounds__(THREADS, 3)
void conv2d_mfma_bf16(const float* __restrict__ x,
                      const float* __restrict__ wts,
                      const float* __restrict__ bias,
                      float* __restrict__ out) {
    // x tile, channel-last bf16: [row][col][16c] -> b128 = 8 consecutive channels
    __shared__ __align__(16) ushort sx[ROWS * COLS * CIN];       // 38016 B
    // weights bf16: [tap][kout][16c]
    __shared__ __align__(16) ushort sw[9 * KOUT * CIN];          // 9216 B

    const int tid = threadIdx.x;
    const int sp  = blockIdx.x;            // 16 h-tiles x 4 w-tiles
    const int n   = blockIdx.y;            // image
    const int hbase = (sp >> 2) * TILE_H;
    const int wbase = (sp & 3) * TILE_W;

    // ---- stage weights: global W[k][c][t] fp32 -> LDS [t][k][c] bf16 (one-time) ----
    for (int i = tid; i < KOUT * CIN * 9; i += THREADS) {
        int k = i / (CIN * 9);
        int rem = i % (CIN * 9);
        int c = rem / 9;
        int t = rem % 9;
        sw[(t * KOUT + k) * CIN + c] = f2bf_rne(wts[i]);
    }

    // ---- stage x tile: quad-channel b64 writes at sequential word addresses ----
    const float* xn = x + (size_t)n * CIN * HH * WW;
    for (int idx = tid; idx < ROWS * COLS * 4; idx += THREADS) {
        int cq = idx & 3;          // channel quad: channels 4cq..4cq+3
        int colrow = idx >> 2;
        int col = colrow % COLS;
        int row = colrow / COLS;
        int gh = hbase - 1 + row;
        int gw = wbase - 1 + col;
        ushort4 pk;
        if ((unsigned)gh < (unsigned)HH && (unsigned)gw < (unsigned)WW) {
            const float* p = xn + ((size_t)(4 * cq) * HH + gh) * WW + gw;
#pragma unroll
            for (int j = 0; j < 4; ++j)
                ((ushort*)&pk)[j] = f2bf_rne(p[(size_t)j * HH * WW]);
        } else {
            pk = make_ushort4(0, 0, 0, 0);
        }
        // element index = (row*COLS+col)*16 + 4cq = idx*4 ; byte addr = idx*8 (8B aligned)
        *reinterpret_cast<ushort4*>(&sx[(size_t)idx * 4]) = pk;
    }
    __syncthreads();

    const int lane = tid & 63;
    const int half = lane >> 5;    // k-dim half: channels half*8..half*8+7
    const int kl   = lane & 31;    // A: kout row / B: pixel col
    const int wave = tid >> 6;

    // ---- A fragments (weights), 9 taps, held in registers ----
    bf16x8 afrag[9];
#pragma unroll
    for (int t = 0; t < 9; ++t)
        afrag[t] = *reinterpret_cast<const bf16x8*>(&sw[(t * KOUT + kl) * CIN + half * 8]);

    const float b0 = bias[0];

    // ---- 32 wave-tiles (16 rows x 2 col-halves), 8 per wave ----
    for (int wt8 = 0; wt8 < 8; ++wt8) {
        const int wt = wave + wt8 * 4;
        const int h  = wt >> 1;            // 0..15 output row within tile
        const int wh = wt & 1;             // 0..1  32-px column half
        f32x16 acc = {};
#pragma unroll
        for (int t = 0; t < 9; ++t) {
            const int r = t / 3, s = t % 3;
            const int lrow = h + r;                 // LDS row (halo offset -1)
            const int lcol = wh * 32 + kl + s;      // LDS col (halo offset -1)
            bf16x8 bfrag = *reinterpret_cast<const bf16x8*>(
                &sx[(lrow * COLS + lcol) * CIN + half * 8]);
            acc = __builtin_amdgcn_mfma_f32_32x32x16_bf16(afrag[t], bfrag, acc, 0, 0, 0);
        }
        // ---- epilogue: D row=kout=(reg&3)+8*(reg>>2)+4*half, col=pixel=kl ----
        const int gh = hbase + h;
        const int gw = wbase + wh * 32 + kl;
#pragma unroll
        for (int reg = 0; reg < 16; ++reg) {
            const int ko = (reg & 3) + 8 * (reg >> 2) + 4 * half;
            out[(((size_t)n * KOUT + ko) * HH + gh) * WW + gw] = acc[reg] + b0;
        }
    }
}

extern "C" void kernel_launch(void* const* d_in, const int* in_sizes, int n_in,
                              void* d_out, int out_size, void* d_ws, size_t ws_size,
                              hipStream_t stream) {
    const float* x    = (const float*)d_in[0];
    const float* wts  = (const float*)d_in[1];
    const float* bias = (const float*)d_in[2];
    float* out = (float*)d_out;

    dim3 grid((HH / TILE_H) * (WW / TILE_W), NIMG);  // (64, 32)
    conv2d_mfma_bf16<<<grid, dim3(THREADS), 0, stream>>>(x, wts, bias, out);
}